// Round 3
// baseline (2852.964 us; speedup 1.0000x reference)
//
#include <hip/hip_runtime.h>
#include <hip/hip_bf16.h>
#include <cstdint>
#include <cstddef>

#define NTOK 2048
#define HID  2048
#define NINT 5632
#define NEXP 8

typedef __attribute__((ext_vector_type(8))) short short8;
typedef __attribute__((ext_vector_type(4))) float f32x4;
typedef __attribute__((ext_vector_type(4))) float fl4;

__device__ __forceinline__ unsigned short f2bf(float f) {
    union { float f; unsigned int u; } v; v.f = f;
    unsigned int r = (v.u + 0x7fffu + ((v.u >> 16) & 1u)) >> 16;
    return (unsigned short)r;
}

// meta layout (ints): [0..7]=cnt, [8..15]=cursor, [16..24]=offs
__global__ void zero_kernel(float* __restrict__ out, int* __restrict__ meta) {
    int idx = blockIdx.x * blockDim.x + threadIdx.x;   // 4096 x 256 fl4 = 16 MB
    fl4 z = {0.f, 0.f, 0.f, 0.f};
    ((fl4*)out)[idx] = z;
    if (blockIdx.x == 0 && threadIdx.x < 16) meta[threadIdx.x] = 0;
}

__device__ __forceinline__ void top2_route(const float* __restrict__ lg, int t,
                                           int& e0, int& e1, float& w0, float& w1) {
    float l[NEXP];
#pragma unroll
    for (int e = 0; e < NEXP; ++e) l[e] = lg[t * NEXP + e];
    e0 = 0; float b0l = l[0];
#pragma unroll
    for (int e = 1; e < NEXP; ++e) if (l[e] > b0l) { b0l = l[e]; e0 = e; }
    e1 = (e0 == 0) ? 1 : 0; float b1l = l[e1];
#pragma unroll
    for (int e = 0; e < NEXP; ++e) {
        if (e == e0) continue;
        if (l[e] > b1l) { b1l = l[e]; e1 = e; }
    }
    float m = b0l;
    float p0 = __expf(b0l - m), p1 = __expf(b1l - m);
    float inv = 1.f / (p0 + p1);
    w0 = p0 * inv; w1 = p1 * inv;
}

__global__ void route_count(const float* __restrict__ logits, int* __restrict__ meta) {
    int t = blockIdx.x * blockDim.x + threadIdx.x;
    int e0, e1; float w0, w1;
    top2_route(logits, t, e0, e1, w0, w1);
    atomicAdd(&meta[e0], 1);
    atomicAdd(&meta[e1], 1);
}

__global__ void scan_kernel(int* __restrict__ meta) {
    if (threadIdx.x == 0 && blockIdx.x == 0) {
        int s = 0;
#pragma unroll
        for (int e = 0; e < NEXP; ++e) { meta[16 + e] = s; s += meta[e]; }
        meta[16 + NEXP] = s;
    }
}

__global__ void route_assign(const float* __restrict__ logits, int* __restrict__ meta,
                             int* __restrict__ rowTok, float* __restrict__ rowW) {
    int t = blockIdx.x * blockDim.x + threadIdx.x;
    int e0, e1; float w0, w1;
    top2_route(logits, t, e0, e1, w0, w1);
    int p0 = atomicAdd(&meta[8 + e0], 1);
    int s0 = meta[16 + e0] + p0;
    rowTok[s0] = t; rowW[s0] = w0;
    int p1 = atomicAdd(&meta[8 + e1], 1);
    int s1 = meta[16 + e1] + p1;
    rowTok[s1] = t; rowW[s1] = w1;
}

__global__ void gather_x(const float* __restrict__ x, const int* __restrict__ rowTok,
                         unsigned short* __restrict__ xg) {
    int slot = blockIdx.x;
    int tok = rowTok[slot];
    int c = threadIdx.x;
    const fl4* src = (const fl4*)(x + (size_t)tok * HID);
    fl4 a = src[c * 2], b = src[c * 2 + 1];
    short8 v;
    v[0] = (short)f2bf(a[0]); v[1] = (short)f2bf(a[1]); v[2] = (short)f2bf(a[2]); v[3] = (short)f2bf(a[3]);
    v[4] = (short)f2bf(b[0]); v[5] = (short)f2bf(b[1]); v[6] = (short)f2bf(b[2]); v[7] = (short)f2bf(b[3]);
    *(short8*)(xg + (size_t)slot * HID + c * 8) = v;
}

// Map blockIdx.y -> (expert, 128-row chunk) via meta offsets.
__device__ __forceinline__ bool find_chunk(const int* __restrict__ meta, int yc,
                                           int& e, int& ch, int& r0, int& Ne) {
    e = -1; ch = 0; int accb = 0;
#pragma unroll
    for (int i = 0; i < NEXP; ++i) {
        int nei = meta[17 + i] - meta[16 + i];
        int cnt = (nei + 127) >> 7;
        if (e < 0 && yc < accb + cnt) { e = i; ch = yc - accb; }
        accb += cnt;
    }
    if (e < 0) return false;
    r0 = meta[16 + e]; Ne = meta[17 + e] - r0;
    return true;
}

// GEMM1 (streaming, no LDS, no syncthreads): each wave = 32 rows x 64 inter cols
// (4 gate frags + 4 up frags). Block = 4 waves = 128 rows. B (fp32 weights)
// streams global->reg->cvt->MFMA with a one-K-step register pipeline; raw
// s_barrier keeps the 4 waves lockstep so their identical B addresses dedup in L1.
__global__ __launch_bounds__(256, 2) void gemm1_kernel(
        const unsigned short* __restrict__ xg,
        const float* __restrict__ w1, const float* __restrict__ w3,
        const int* __restrict__ meta, unsigned short* __restrict__ act) {
    int it = blockIdx.x;            // 88 tiles of 64 inter cols
    int e, ch, r0, Ne;
    if (!find_chunk(meta, blockIdx.y, e, ch, r0, Ne)) return;

    int lane = threadIdx.x & 63, w = threadIdx.x >> 6;
    int cl = lane & 15, kq = lane >> 4;
    int rowb = ch * 128 + w * 32;

    int ra0 = rowb + cl;      if (ra0 > Ne - 1) ra0 = Ne - 1;
    int ra1 = rowb + 16 + cl; if (ra1 > Ne - 1) ra1 = Ne - 1;
    const unsigned short* a0p = xg + (size_t)(r0 + ra0) * HID + kq * 8;
    const unsigned short* a1p = xg + (size_t)(r0 + ra1) * HID + kq * 8;

    const float* bp[8];
#pragma unroll
    for (int f = 0; f < 4; ++f) {
        bp[f]     = w1 + ((size_t)e * NINT + it * 64 + f * 16 + cl) * HID + kq * 8;
        bp[f + 4] = w3 + ((size_t)e * NINT + it * 64 + f * 16 + cl) * HID + kq * 8;
    }

    f32x4 acc[2][8];
#pragma unroll
    for (int m = 0; m < 2; ++m)
#pragma unroll
        for (int f = 0; f < 8; ++f) acc[m][f] = (f32x4){0.f, 0.f, 0.f, 0.f};

    fl4 b0[8], b1[8];
#pragma unroll
    for (int f = 0; f < 8; ++f) { b0[f] = *(const fl4*)(bp[f]); b1[f] = *(const fl4*)(bp[f] + 4); }
    short8 a0 = *(const short8*)a0p;
    short8 a1 = *(const short8*)a1p;

#pragma unroll 1
    for (int k0 = 0; k0 < HID; k0 += 32) {
        __builtin_amdgcn_s_barrier();          // raw barrier: no vmcnt drain
        int kn = (k0 + 32 < HID) ? (k0 + 32) : 0;
        short8 a0n = *(const short8*)(a0p + kn);
        short8 a1n = *(const short8*)(a1p + kn);
#pragma unroll
        for (int f = 0; f < 8; ++f) {
            short8 bb;
#pragma unroll
            for (int i = 0; i < 4; ++i) { bb[i] = (short)f2bf(b0[f][i]); bb[i + 4] = (short)f2bf(b1[f][i]); }
            b0[f] = *(const fl4*)(bp[f] + kn);          // next step, in flight during MFMA
            b1[f] = *(const fl4*)(bp[f] + kn + 4);
            acc[0][f] = __builtin_amdgcn_mfma_f32_16x16x32_bf16(a0, bb, acc[0][f], 0, 0, 0);
            acc[1][f] = __builtin_amdgcn_mfma_f32_16x16x32_bf16(a1, bb, acc[1][f], 0, 0, 0);
        }
        a0 = a0n; a1 = a1n;
    }

    // epilogue: y = silu(gate) * up -> act bf16  (C layout: col=lane&15, row=kq*4+j)
#pragma unroll
    for (int m = 0; m < 2; ++m) {
#pragma unroll
        for (int f = 0; f < 4; ++f) {
            f32x4 g = acc[m][f], u = acc[m][f + 4];
#pragma unroll
            for (int j = 0; j < 4; ++j) {
                int lr = rowb + m * 16 + kq * 4 + j;
                if (lr < Ne) {
                    float gv = g[j];
                    float y = gv / (1.f + __expf(-gv)) * u[j];
                    act[(size_t)(r0 + lr) * NINT + it * 64 + f * 16 + cl] = f2bf(y);
                }
            }
        }
    }
}

// GEMM2 (same streaming structure): wave = 32 rows x 128 hid cols (8 frags),
// K = NINT. Scaled fp32 atomicAdd into out.
__global__ __launch_bounds__(256, 2) void gemm2_kernel(
        const unsigned short* __restrict__ act, const float* __restrict__ w2,
        const int* __restrict__ meta, const int* __restrict__ rowTok,
        const float* __restrict__ rowW, float* __restrict__ out) {
    int ht = blockIdx.x;            // 16 tiles of 128 hid cols
    int e, ch, r0, Ne;
    if (!find_chunk(meta, blockIdx.y, e, ch, r0, Ne)) return;

    int lane = threadIdx.x & 63, w = threadIdx.x >> 6;
    int cl = lane & 15, kq = lane >> 4;
    int rowb = ch * 128 + w * 32;

    int ra0 = rowb + cl;      if (ra0 > Ne - 1) ra0 = Ne - 1;
    int ra1 = rowb + 16 + cl; if (ra1 > Ne - 1) ra1 = Ne - 1;
    const unsigned short* a0p = act + (size_t)(r0 + ra0) * NINT + kq * 8;
    const unsigned short* a1p = act + (size_t)(r0 + ra1) * NINT + kq * 8;

    const float* bp[8];
#pragma unroll
    for (int f = 0; f < 8; ++f)
        bp[f] = w2 + ((size_t)e * HID + ht * 128 + f * 16 + cl) * NINT + kq * 8;

    f32x4 acc[2][8];
#pragma unroll
    for (int m = 0; m < 2; ++m)
#pragma unroll
        for (int f = 0; f < 8; ++f) acc[m][f] = (f32x4){0.f, 0.f, 0.f, 0.f};

    fl4 b0[8], b1[8];
#pragma unroll
    for (int f = 0; f < 8; ++f) { b0[f] = *(const fl4*)(bp[f]); b1[f] = *(const fl4*)(bp[f] + 4); }
    short8 a0 = *(const short8*)a0p;
    short8 a1 = *(const short8*)a1p;

#pragma unroll 1
    for (int k0 = 0; k0 < NINT; k0 += 32) {
        __builtin_amdgcn_s_barrier();
        int kn = (k0 + 32 < NINT) ? (k0 + 32) : 0;
        short8 a0n = *(const short8*)(a0p + kn);
        short8 a1n = *(const short8*)(a1p + kn);
#pragma unroll
        for (int f = 0; f < 8; ++f) {
            short8 bb;
#pragma unroll
            for (int i = 0; i < 4; ++i) { bb[i] = (short)f2bf(b0[f][i]); bb[i + 4] = (short)f2bf(b1[f][i]); }
            b0[f] = *(const fl4*)(bp[f] + kn);
            b1[f] = *(const fl4*)(bp[f] + kn + 4);
            acc[0][f] = __builtin_amdgcn_mfma_f32_16x16x32_bf16(a0, bb, acc[0][f], 0, 0, 0);
            acc[1][f] = __builtin_amdgcn_mfma_f32_16x16x32_bf16(a1, bb, acc[1][f], 0, 0, 0);
        }
        a0 = a0n; a1 = a1n;
    }

#pragma unroll
    for (int m = 0; m < 2; ++m) {
#pragma unroll
        for (int j = 0; j < 4; ++j) {
            int lr = rowb + m * 16 + kq * 4 + j;
            if (lr < Ne) {
                int slot = r0 + lr;
                int tok = rowTok[slot];
                float sw = rowW[slot];
#pragma unroll
                for (int f = 0; f < 8; ++f)
                    atomicAdd(&out[(size_t)tok * HID + ht * 128 + f * 16 + cl], acc[m][f][j] * sw);
            }
        }
    }
}

extern "C" void kernel_launch(void* const* d_in, const int* in_sizes, int n_in,
                              void* d_out, int out_size, void* d_ws, size_t ws_size,
                              hipStream_t stream) {
    const float* x      = (const float*)d_in[0];
    const float* logits = (const float*)d_in[1];
    const float* w1     = (const float*)d_in[2];
    const float* w3     = (const float*)d_in[3];
    const float* w2     = (const float*)d_in[4];
    float* out = (float*)d_out;

    char* ws = (char*)d_ws;
    int*   meta   = (int*)ws;                       // 32 ints
    int*   rowTok = (int*)(ws + 512);               // 4096 ints
    float* rowW   = (float*)(ws + 512 + 16384);     // 4096 floats
    unsigned short* xg  = (unsigned short*)(ws + (1u << 20));   // 16 MB
    unsigned short* act = (unsigned short*)(ws + (18u << 20));  // 44 MB

    zero_kernel<<<4096, 256, 0, stream>>>(out, meta);
    route_count<<<8, 256, 0, stream>>>(logits, meta);
    scan_kernel<<<1, 1, 0, stream>>>(meta);
    route_assign<<<8, 256, 0, stream>>>(logits, meta, rowTok, rowW);
    gather_x<<<4096, 256, 0, stream>>>(x, rowTok, xg);
    gemm1_kernel<<<dim3(88, 40), 256, 0, stream>>>(xg, w1, w3, meta, act);
    gemm2_kernel<<<dim3(16, 40), 256, 0, stream>>>(act, w2, meta, rowTok, rowW, out);
}